// Round 4
// baseline (3936.279 us; speedup 1.0000x reference)
//
#include <hip/hip_runtime.h>
#include <hip/hip_bf16.h>

// LSMPool round 4:
//  - k_step v3: NO LDS in the GEMM. With N=16/block, LDS staging has zero
//    reuse over direct L1/L2 fragment gathers (164MB either way), so A/B
//    fragments load straight global->VGPR (16 rows x 16B; s0/s1 chunks of a
//    row share a 128B line). Depth-3 register pipeline (compiler emits
//    counted vmcnt for reg dataflow). 512 thr = 8 waves = 2/SIMD (round 3
//    ran 1/SIMD; stalls had no cover). 8-way K-split (KW=640, 10 windows of
//    BK=64). LDS only for the 32KB epilogue reduce + LIF.
//  - k_ro_gemm v2: round-2's verified swizzled BK=64 double-buffered tile
//    (bank conflicts measured 0) + bijective XCD swizzle (1024%8==0).
//  - prep + ro_scan unchanged.

namespace {
constexpr int T_STEPS = 128;
constexpr int BATCH   = 64;
constexpr int IN_F    = 1024;
constexpr int HID     = 4096;
constexpr int OUT_F   = 512;
constexpr int TOTAL   = IN_F + HID;    // 5120
constexpr int NWAVE   = 8;
constexpr int KW      = TOTAL / NWAVE; // 640 per wave
constexpr int BK      = 64;
constexpr int NIT     = KW / BK;       // 10 windows per wave
}

using bf16x8 = __attribute__((ext_vector_type(8))) short;
using f32x4  = __attribute__((ext_vector_type(4))) float;

// ---------------- prep kernels ----------------

__global__ void k_cvt_split(const float* __restrict__ src,
                            __hip_bfloat16* __restrict__ hi,
                            __hip_bfloat16* __restrict__ lo, int n4) {
  int i = blockIdx.x * blockDim.x + threadIdx.x;
  if (i >= n4) return;
  float4 v = reinterpret_cast<const float4*>(src)[i];
#define CVT1(J, F)                                                        \
  {                                                                       \
    __hip_bfloat16 hb = __float2bfloat16(F);                              \
    hi[4 * (size_t)i + J] = hb;                                           \
    lo[4 * (size_t)i + J] = __float2bfloat16((F) - __bfloat162float(hb)); \
  }
  CVT1(0, v.x) CVT1(1, v.y) CVT1(2, v.z) CVT1(3, v.w)
#undef CVT1
}

__global__ void k_cvt_x(const float* __restrict__ src,
                        __hip_bfloat16* __restrict__ dst, int n) {
  int i = blockIdx.x * blockDim.x + threadIdx.x;
  if (i >= n) return;
  dst[i] = __float2bfloat16(src[i]);
}

__global__ void k_zero(float* __restrict__ mem1, ushort* __restrict__ spk0, int n) {
  int i = blockIdx.x * blockDim.x + threadIdx.x;
  if (i >= n) return;
  mem1[i] = 0.0f;
  spk0[i] = 0;  // bf16 +0.0
}

// ---------------- per-step fused GEMM + LIF (no-LDS gather GEMM) ----------
// 256 blocks x 512 thr. Block: N=16 hidden units, M=64 batch, full K=5120.
// Wave wv (0..7): K-range [wv*640, wv*640+640), 10 windows of BK=64.
__global__ __launch_bounds__(512, 2)
void k_step(int t,
            const __hip_bfloat16* __restrict__ xb,    // [T][B][IN_F]
            __hip_bfloat16* __restrict__ spk,         // [T+1][B][HID]
            const __hip_bfloat16* __restrict__ w1hi,  // [HID][TOTAL]
            const __hip_bfloat16* __restrict__ w1lo,
            float* __restrict__ mem1,                 // [B][HID]
            const float* __restrict__ beta,           // [HID]
            const float* __restrict__ thr) {          // [HID]
  __shared__ float red[NWAVE * 1024];   // 32 KB

  const int tid   = threadIdx.x;
  const int l     = tid & 63;
  const int wv    = tid >> 6;           // 0..7
  const int nbase = blockIdx.x * 16;
  const int kwave = wv * KW;

  const __hip_bfloat16* xbt  = xb  + (size_t)t * BATCH * IN_F;
  const __hip_bfloat16* spkt = spk + (size_t)t * BATCH * HID;

  const int fr = l & 15;        // fragment row
  const int fk = (l >> 4) * 8;  // fragment k-chunk (8 elems)

  // per-lane element offsets (A rows = batch; B rows = w1 output units)
  int aoffX[4], aoffS[4];
#pragma unroll
  for (int mf = 0; mf < 4; ++mf) {
    aoffX[mf] = (mf * 16 + fr) * IN_F + fk;
    aoffS[mf] = (mf * 16 + fr) * HID + fk;
  }
  const __hip_bfloat16* pBh = w1hi + (size_t)(nbase + fr) * TOTAL + fk;
  const __hip_bfloat16* pBl = w1lo + (size_t)(nbase + fr) * TOTAL + fk;

  f32x4 acc[4];
#pragma unroll
  for (int mf = 0; mf < 4; ++mf) acc[mf] = (f32x4){0.f, 0.f, 0.f, 0.f};

  struct Win { bf16x8 a[4][2]; bf16x8 bh[2]; bf16x8 bl[2]; };  // 48 VGPR
  Win wn0, wn1, wn2;

  auto LOADW = [&](int i, Win& W) {
    const int k0 = kwave + i * BK;   // windows never straddle the 1024 boundary
    if (k0 < IN_F) {
      const __hip_bfloat16* base = xbt + k0;
#pragma unroll
      for (int mf = 0; mf < 4; ++mf) {
        W.a[mf][0] = *(const bf16x8*)(base + aoffX[mf]);
        W.a[mf][1] = *(const bf16x8*)(base + aoffX[mf] + 32);
      }
    } else {
      const __hip_bfloat16* base = spkt + (k0 - IN_F);
#pragma unroll
      for (int mf = 0; mf < 4; ++mf) {
        W.a[mf][0] = *(const bf16x8*)(base + aoffS[mf]);
        W.a[mf][1] = *(const bf16x8*)(base + aoffS[mf] + 32);
      }
    }
    W.bh[0] = *(const bf16x8*)(pBh + k0);
    W.bh[1] = *(const bf16x8*)(pBh + k0 + 32);
    W.bl[0] = *(const bf16x8*)(pBl + k0);
    W.bl[1] = *(const bf16x8*)(pBl + k0 + 32);
  };

  auto COMPW = [&](Win& W) {
#pragma unroll
    for (int s = 0; s < 2; ++s) {
#pragma unroll
      for (int mf = 0; mf < 4; ++mf) {
        acc[mf] = __builtin_amdgcn_mfma_f32_16x16x32_bf16(W.a[mf][s], W.bh[s],
                                                          acc[mf], 0, 0, 0);
        acc[mf] = __builtin_amdgcn_mfma_f32_16x16x32_bf16(W.a[mf][s], W.bl[s],
                                                          acc[mf], 0, 0, 0);
      }
    }
  };

  // depth-3 register pipeline, fully unrolled (static buffer names)
  LOADW(0, wn0);
  LOADW(1, wn1);
  LOADW(2, wn2);
#define ITER(i, W)                      \
  COMPW(W);                             \
  if ((i) + 3 < NIT) LOADW((i) + 3, W);
  ITER(0, wn0) ITER(1, wn1) ITER(2, wn2)
  ITER(3, wn0) ITER(4, wn1) ITER(5, wn2)
  ITER(6, wn0) ITER(7, wn1) ITER(8, wn2)
  ITER(9, wn0)
#undef ITER

  // --- cross-wave reduce (fixed order = deterministic) + LIF ---
  __syncthreads();
#pragma unroll
  for (int mf = 0; mf < 4; ++mf) {
#pragma unroll
    for (int q = 0; q < 4; ++q) {
      const int m = mf * 16 + (l >> 4) * 4 + q;   // batch row
      red[wv * 1024 + m * 16 + fr] = acc[mf][q];
    }
  }
  __syncthreads();

  __hip_bfloat16* spk_out = spk + (size_t)(t + 1) * BATCH * HID;
#pragma unroll
  for (int u = 0; u < 2; ++u) {
    const int o = tid + u * 512;                  // m*16 + n, 0..1023
    float c = red[o];
#pragma unroll
    for (int k2 = 1; k2 < NWAVE; ++k2) c += red[k2 * 1024 + o];
    const int m  = o >> 4;
    const int ng = nbase + (o & 15);
    const size_t gi = (size_t)m * HID + ng;
    float mv = mem1[gi] - beta[ng] + c;
    mv = fmaxf(mv, 0.f);                          // state_quant = relu
    const float s = (mv > thr[ng]) ? 1.f : 0.f;
    mv -= s * thr[ng];                            // reset by subtract
    mem1[gi] = mv;
    spk_out[gi] = __float2bfloat16(s);
  }
}

// ---------------- readout GEMM v2: cur2 = spk_rec @ w2^T + b2 -------------
// M=8192, N=512, K=4096. 1024 blocks (128 mt x 8 nt, XCD-swizzled), 256 thr,
// 64x64 tile, BK=64 double-buffered LDS with XOR swizzle (round-2 formulas).
__global__ __launch_bounds__(256, 2)
void k_ro_gemm(const __hip_bfloat16* __restrict__ A,      // [8192][HID]
               const __hip_bfloat16* __restrict__ w2hi,   // [OUT_F][HID]
               const __hip_bfloat16* __restrict__ w2lo,
               const float* __restrict__ b2,
               float* __restrict__ cur2) {                // [8192][OUT_F]
  __shared__ __align__(16) short lA[2][64 * BK];
  __shared__ __align__(16) short lBh[2][64 * BK];
  __shared__ __align__(16) short lBl[2][64 * BK];

  const int tid  = threadIdx.x;
  const int lane = tid & 63;
  const int w    = tid >> 6;

  // bijective XCD swizzle: 1024 blocks, 8 XCDs -> chunk of 128 per XCD;
  // within a chunk, consecutive blocks share the A (m) tile.
  const int xcd = blockIdx.x & 7;
  const int c   = blockIdx.x >> 3;       // 0..127
  const int mt  = xcd * 16 + (c >> 3);   // 0..127
  const int nt  = c & 7;                 // 0..7
  const int mbase = mt * 64;
  const int nbase = nt * 64;

  // staging geometry (round-2 verified): thread stages 2x16B of one tile row
  const int rS   = tid >> 2;
  const int cEl  = (tid & 3) * 16;
  const int swzX = (rS & 7) << 4;
  const int stByte0 = rS * 128 + ((cEl * 2) ^ swzX);
  const int stByte1 = rS * 128 + ((cEl * 2 + 16) ^ swzX);

  // fragment geometry
  const int fr    = lane & 15;
  const int fkB   = (lane >> 4) * 16;
  const int frSwz = (fr & 7) << 4;

  f32x4 acc[4];
#pragma unroll
  for (int m = 0; m < 4; ++m) acc[m] = (f32x4){0.f, 0.f, 0.f, 0.f};
  bf16x8 rgA[6], rgB[6];

  auto GLOAD = [&](int it, bf16x8* R) {
    const int k0 = it * BK;
    const __hip_bfloat16* asrc = A    + (size_t)(mbase + rS) * HID + k0 + cEl;
    const __hip_bfloat16* hsrc = w2hi + (size_t)(nbase + rS) * HID + k0 + cEl;
    const __hip_bfloat16* lsrc = w2lo + (size_t)(nbase + rS) * HID + k0 + cEl;
    R[0] = *(const bf16x8*)(asrc);
    R[1] = *(const bf16x8*)(asrc + 8);
    R[2] = *(const bf16x8*)(hsrc);
    R[3] = *(const bf16x8*)(hsrc + 8);
    R[4] = *(const bf16x8*)(lsrc);
    R[5] = *(const bf16x8*)(lsrc + 8);
  };
  auto DSWRITE = [&](int ibuf, bf16x8* R) {
    *(bf16x8*)((char*)lA[ibuf] + stByte0)  = R[0];
    *(bf16x8*)((char*)lA[ibuf] + stByte1)  = R[1];
    *(bf16x8*)((char*)lBh[ibuf] + stByte0) = R[2];
    *(bf16x8*)((char*)lBh[ibuf] + stByte1) = R[3];
    *(bf16x8*)((char*)lBl[ibuf] + stByte0) = R[4];
    *(bf16x8*)((char*)lBl[ibuf] + stByte1) = R[5];
  };
  auto COMPUTE = [&](int ibuf) {
    const char* pA  = (const char*)lA[ibuf];
    const char* pBh = (const char*)lBh[ibuf];
    const char* pBl = (const char*)lBl[ibuf];
#pragma unroll
    for (int s = 0; s < 2; ++s) {
      const int co = ((s * 64 + fkB) ^ frSwz);
      bf16x8 fbh = *(const bf16x8*)(pBh + (w * 16 + fr) * 128 + co);
      bf16x8 fbl = *(const bf16x8*)(pBl + (w * 16 + fr) * 128 + co);
#pragma unroll
      for (int m = 0; m < 4; ++m) {
        bf16x8 fa = *(const bf16x8*)(pA + (m * 16 + fr) * 128 + co);
        acc[m] = __builtin_amdgcn_mfma_f32_16x16x32_bf16(fa, fbh, acc[m], 0, 0, 0);
        acc[m] = __builtin_amdgcn_mfma_f32_16x16x32_bf16(fa, fbl, acc[m], 0, 0, 0);
      }
    }
  };

  constexpr int RNIT = HID / BK;  // 64
  GLOAD(0, rgA);
  DSWRITE(0, rgA);
  __syncthreads();
  for (int itp = 0; itp < RNIT / 2; ++itp) {
    const int it = itp * 2;
    GLOAD(it + 1, rgB);
    COMPUTE(0);
    DSWRITE(1, rgB);
    __syncthreads();
    if (it + 2 < RNIT) {
      GLOAD(it + 2, rgA);
      COMPUTE(1);
      DSWRITE(0, rgA);
      __syncthreads();
    } else {
      COMPUTE(1);
    }
  }

  const int col = nbase + w * 16 + fr;
  const float bias = b2[col];
  const int brow = (lane >> 4) * 4;
#pragma unroll
  for (int m = 0; m < 4; ++m) {
#pragma unroll
    for (int q = 0; q < 4; ++q) {
      const int row = mbase + m * 16 + brow + q;
      cur2[(size_t)row * OUT_F + col] = acc[m][q] + bias;
    }
  }
}

// ---------------- readout LIF scan ----------------
__global__ void k_ro_scan(const float* __restrict__ cur2,
                          const float* __restrict__ beta,
                          const float* __restrict__ thr,
                          float* __restrict__ out) {
  const int i = blockIdx.x * blockDim.x + threadIdx.x;
  const int b = i >> 9;
  const int o = i & (OUT_F - 1);
  const float bt = beta[o];
  const float th = thr[o];
  float m = 0.0f;
  for (int t = 0; t < T_STEPS; ++t) {
    const size_t idx = (size_t)(t * BATCH + b) * OUT_F + o;
    m = m - bt + cur2[idx];
    const float s = (m > th) ? 1.0f : 0.0f;
    m -= s * th;
    out[idx] = s;
  }
}

// ---------------- launch ----------------
extern "C" void kernel_launch(void* const* d_in, const int* in_sizes, int n_in,
                              void* d_out, int out_size, void* d_ws, size_t ws_size,
                              hipStream_t stream) {
  const float* x        = (const float*)d_in[0];
  const float* w1       = (const float*)d_in[1];
  const float* w2       = (const float*)d_in[2];
  const float* b2       = (const float*)d_in[3];
  const float* beta_lsm = (const float*)d_in[4];
  const float* thr_lsm  = (const float*)d_in[5];
  const float* beta_ro  = (const float*)d_in[6];
  const float* thr_ro   = (const float*)d_in[7];
  float* out = (float*)d_out;

  char* ws = (char*)d_ws;
  size_t off = 0;
  auto alloc = [&](size_t bytes) -> char* {
    char* p = ws + off;
    off += (bytes + 255) & ~(size_t)255;
    return p;
  };
  __hip_bfloat16* w1hi = (__hip_bfloat16*)alloc((size_t)HID * TOTAL * 2);
  __hip_bfloat16* w1lo = (__hip_bfloat16*)alloc((size_t)HID * TOTAL * 2);
  __hip_bfloat16* xb   = (__hip_bfloat16*)alloc((size_t)T_STEPS * BATCH * IN_F * 2);
  __hip_bfloat16* spk  = (__hip_bfloat16*)alloc((size_t)(T_STEPS + 1) * BATCH * HID * 2);
  __hip_bfloat16* w2hi = (__hip_bfloat16*)alloc((size_t)OUT_F * HID * 2);
  __hip_bfloat16* w2lo = (__hip_bfloat16*)alloc((size_t)OUT_F * HID * 2);
  float* mem1 = (float*)alloc((size_t)BATCH * HID * 4);
  float* cur2 = (float*)alloc((size_t)T_STEPS * BATCH * OUT_F * 4);

  // prep
  {
    int n4 = HID * TOTAL / 4;
    k_cvt_split<<<(n4 + 255) / 256, 256, 0, stream>>>(w1, w1hi, w1lo, n4);
  }
  {
    int n4 = OUT_F * HID / 4;
    k_cvt_split<<<(n4 + 255) / 256, 256, 0, stream>>>(w2, w2hi, w2lo, n4);
  }
  {
    int n = T_STEPS * BATCH * IN_F;
    k_cvt_x<<<(n + 255) / 256, 256, 0, stream>>>(x, xb, n);
  }
  {
    int n = BATCH * HID;
    k_zero<<<(n + 255) / 256, 256, 0, stream>>>(mem1, (ushort*)spk, n);
  }

  // sequential reservoir steps: one kernel per step (stream order = sync)
  for (int t = 0; t < T_STEPS; ++t) {
    k_step<<<HID / 16, 512, 0, stream>>>(t, xb, spk, w1hi, w1lo, mem1,
                                         beta_lsm, thr_lsm);
  }

  // readout
  k_ro_gemm<<<(T_STEPS * BATCH / 64) * (OUT_F / 64), 256, 0, stream>>>(
      spk + (size_t)BATCH * HID, w2hi, w2lo, b2, cur2);
  k_ro_scan<<<(BATCH * OUT_F) / 256, 256, 0, stream>>>(cur2, beta_ro, thr_ro, out);
}

// Round 5
// 3131.905 us; speedup vs baseline: 1.2568x; 1.2568x over previous
//
#include <hip/hip_runtime.h>
#include <hip/hip_bf16.h>

// LSMPool round 5: within-round A/B on the step kernel.
//   even t -> k_stepA: round-3 LDS-staged kernel VERBATIM (proven ~17us/step).
//   odd  t -> k_stepB: round-4 register-gather kernel, sole change =
//             __launch_bounds__(512,1) (remove any VGPR/occupancy cap).
// Decides: gather regression = occupancy artifact (H1) vs structural (H2).
// ro_gemm v2 (swizzled, XCD-remapped; 105us, 0 bank conflicts) unchanged.

namespace {
constexpr int T_STEPS = 128;
constexpr int BATCH   = 64;
constexpr int IN_F    = 1024;
constexpr int HID     = 4096;
constexpr int OUT_F   = 512;
constexpr int TOTAL   = IN_F + HID;    // 5120
constexpr int BK      = 64;
// variant A (4 waves, LDS triple-buffer)
constexpr int NWAVE_A = 4;
constexpr int KW_A    = TOTAL / NWAVE_A; // 1280
constexpr int NIT_A   = KW_A / BK;       // 20
constexpr int BUFB    = 12288;           // A 8KB + Bh 2KB + Bl 2KB
constexpr int WREGB   = 3 * BUFB;        // 36864
constexpr int SMEMB   = NWAVE_A * WREGB; // 147456
// variant B (8 waves, register pipeline)
constexpr int NWAVE_B = 8;
constexpr int KW_B    = TOTAL / NWAVE_B; // 640
constexpr int NIT_B   = KW_B / BK;       // 10
}

using bf16x8 = __attribute__((ext_vector_type(8))) short;
using f32x4  = __attribute__((ext_vector_type(4))) float;

__device__ __forceinline__ void gload_lds16(const void* g, void* l) {
  __builtin_amdgcn_global_load_lds(
      (const __attribute__((address_space(1))) unsigned int*)(g),
      (__attribute__((address_space(3))) unsigned int*)(l), 16, 0, 0);
}

// ---------------- prep kernels ----------------

__global__ void k_cvt_split(const float* __restrict__ src,
                            __hip_bfloat16* __restrict__ hi,
                            __hip_bfloat16* __restrict__ lo, int n4) {
  int i = blockIdx.x * blockDim.x + threadIdx.x;
  if (i >= n4) return;
  float4 v = reinterpret_cast<const float4*>(src)[i];
#define CVT1(J, F)                                                        \
  {                                                                       \
    __hip_bfloat16 hb = __float2bfloat16(F);                              \
    hi[4 * (size_t)i + J] = hb;                                           \
    lo[4 * (size_t)i + J] = __float2bfloat16((F) - __bfloat162float(hb)); \
  }
  CVT1(0, v.x) CVT1(1, v.y) CVT1(2, v.z) CVT1(3, v.w)
#undef CVT1
}

__global__ void k_cvt_x(const float* __restrict__ src,
                        __hip_bfloat16* __restrict__ dst, int n) {
  int i = blockIdx.x * blockDim.x + threadIdx.x;
  if (i >= n) return;
  dst[i] = __float2bfloat16(src[i]);
}

__global__ void k_zero(float* __restrict__ mem1, ushort* __restrict__ spk0, int n) {
  int i = blockIdx.x * blockDim.x + threadIdx.x;
  if (i >= n) return;
  mem1[i] = 0.0f;
  spk0[i] = 0;  // bf16 +0.0
}

// ================= variant A: LDS-staged (round 3 verbatim) =================
__global__ __launch_bounds__(256, 1)
void k_stepA(int t,
             const __hip_bfloat16* __restrict__ xb,
             __hip_bfloat16* __restrict__ spk,
             const __hip_bfloat16* __restrict__ w1hi,
             const __hip_bfloat16* __restrict__ w1lo,
             float* __restrict__ mem1,
             const float* __restrict__ beta,
             const float* __restrict__ thr) {
  __shared__ __align__(16) char smem[SMEMB];

  const int tid   = threadIdx.x;
  const int l     = tid & 63;
  const int wv    = tid >> 6;
  const int nbase = blockIdx.x * 16;
  const int kwave = wv * KW_A;

  const __hip_bfloat16* xbt  = xb  + (size_t)t * BATCH * IN_F;
  const __hip_bfloat16* spkt = spk + (size_t)t * BATCH * HID;

  const int jrow = l >> 3;
  const int swz  = ((l & 7) ^ jrow) * 8;
  const int aX = jrow * IN_F + swz;
  const int aS = jrow * HID + swz;
  const int bO = jrow * TOTAL + swz;

  const int rA  = (l & 15) * 128;
  const int cs0 = (((l >> 4) ^ (l & 7)) * 16);
  const int cs1 = ((((l >> 4) + 4) ^ (l & 7)) * 16);

  char* const wbase = smem + (size_t)wv * WREGB;

  f32x4 acc[4];
#pragma unroll
  for (int mf = 0; mf < 4; ++mf) acc[mf] = (f32x4){0.f, 0.f, 0.f, 0.f};

  auto ISSUE = [&](int it, char* ldsw) {
    const int k0 = kwave + it * BK;
    if (k0 < IN_F) {
      const __hip_bfloat16* ab = xbt + k0 + aX;
#pragma unroll
      for (int j = 0; j < 8; ++j)
        gload_lds16(ab + j * 8 * IN_F, ldsw + j * 1024);
    } else {
      const __hip_bfloat16* ab = spkt + (k0 - IN_F) + aS;
#pragma unroll
      for (int j = 0; j < 8; ++j)
        gload_lds16(ab + j * 8 * HID, ldsw + j * 1024);
    }
    const __hip_bfloat16* hb = w1hi + (size_t)nbase * TOTAL + k0 + bO;
    const __hip_bfloat16* lb = w1lo + (size_t)nbase * TOTAL + k0 + bO;
    gload_lds16(hb,             ldsw + 8192);
    gload_lds16(hb + 8 * TOTAL, ldsw + 9216);
    gload_lds16(lb,             ldsw + 10240);
    gload_lds16(lb + 8 * TOTAL, ldsw + 11264);
  };

  auto COMP = [&](char* ldsw) {
#pragma unroll
    for (int s = 0; s < 2; ++s) {
      const int cs = s ? cs1 : cs0;
      bf16x8 bh = *(const bf16x8*)(ldsw + 8192  + rA + cs);
      bf16x8 bl = *(const bf16x8*)(ldsw + 10240 + rA + cs);
#pragma unroll
      for (int mf = 0; mf < 4; ++mf) {
        bf16x8 a = *(const bf16x8*)(ldsw + mf * 2048 + rA + cs);
        acc[mf] = __builtin_amdgcn_mfma_f32_16x16x32_bf16(a, bh, acc[mf], 0, 0, 0);
        acc[mf] = __builtin_amdgcn_mfma_f32_16x16x32_bf16(a, bl, acc[mf], 0, 0, 0);
      }
    }
  };

  char* p0 = wbase;
  char* p1 = wbase + BUFB;
  char* p2 = wbase + 2 * BUFB;
  ISSUE(0, p0);
  ISSUE(1, p1);
  ISSUE(2, p2);
  for (int i = 0; i < NIT_A - 3; ++i) {
    asm volatile("s_waitcnt vmcnt(24)" ::: "memory");
    COMP(p0);
    ISSUE(i + 3, p0);
    char* tmp = p0; p0 = p1; p1 = p2; p2 = tmp;
  }
  asm volatile("s_waitcnt vmcnt(24)" ::: "memory");
  COMP(p0);
  asm volatile("s_waitcnt vmcnt(12)" ::: "memory");
  COMP(p1);
  asm volatile("s_waitcnt vmcnt(0)" ::: "memory");
  COMP(p2);

  __syncthreads();
  float* red = (float*)smem;
#pragma unroll
  for (int mf = 0; mf < 4; ++mf) {
#pragma unroll
    for (int q = 0; q < 4; ++q) {
      const int m = mf * 16 + (l >> 4) * 4 + q;
      red[wv * 1024 + m * 16 + (l & 15)] = acc[mf][q];
    }
  }
  __syncthreads();

  __hip_bfloat16* spk_out = spk + (size_t)(t + 1) * BATCH * HID;
#pragma unroll
  for (int u = 0; u < 4; ++u) {
    const int o = tid + u * 256;
    const float c = (red[o] + red[o + 1024]) + (red[o + 2048] + red[o + 3072]);
    const int m  = o >> 4;
    const int ng = nbase + (o & 15);
    const size_t gi = (size_t)m * HID + ng;
    float mv = mem1[gi] - beta[ng] + c;
    mv = fmaxf(mv, 0.f);
    const float s = (mv > thr[ng]) ? 1.f : 0.f;
    mv -= s * thr[ng];
    mem1[gi] = mv;
    spk_out[gi] = __float2bfloat16(s);
  }
}

// ============ variant B: register-gather (round 4, relaxed bounds) ==========
__global__ __launch_bounds__(512, 1)
void k_stepB(int t,
             const __hip_bfloat16* __restrict__ xb,
             __hip_bfloat16* __restrict__ spk,
             const __hip_bfloat16* __restrict__ w1hi,
             const __hip_bfloat16* __restrict__ w1lo,
             float* __restrict__ mem1,
             const float* __restrict__ beta,
             const float* __restrict__ thr) {
  __shared__ float red[NWAVE_B * 1024];   // 32 KB

  const int tid   = threadIdx.x;
  const int l     = tid & 63;
  const int wv    = tid >> 6;
  const int nbase = blockIdx.x * 16;
  const int kwave = wv * KW_B;

  const __hip_bfloat16* xbt  = xb  + (size_t)t * BATCH * IN_F;
  const __hip_bfloat16* spkt = spk + (size_t)t * BATCH * HID;

  const int fr = l & 15;
  const int fk = (l >> 4) * 8;

  int aoffX[4], aoffS[4];
#pragma unroll
  for (int mf = 0; mf < 4; ++mf) {
    aoffX[mf] = (mf * 16 + fr) * IN_F + fk;
    aoffS[mf] = (mf * 16 + fr) * HID + fk;
  }
  const __hip_bfloat16* pBh = w1hi + (size_t)(nbase + fr) * TOTAL + fk;
  const __hip_bfloat16* pBl = w1lo + (size_t)(nbase + fr) * TOTAL + fk;

  f32x4 acc[4];
#pragma unroll
  for (int mf = 0; mf < 4; ++mf) acc[mf] = (f32x4){0.f, 0.f, 0.f, 0.f};

  struct Win { bf16x8 a[4][2]; bf16x8 bh[2]; bf16x8 bl[2]; };
  Win wn0, wn1, wn2;

  auto LOADW = [&](int i, Win& W) {
    const int k0 = kwave + i * BK;
    if (k0 < IN_F) {
      const __hip_bfloat16* base = xbt + k0;
#pragma unroll
      for (int mf = 0; mf < 4; ++mf) {
        W.a[mf][0] = *(const bf16x8*)(base + aoffX[mf]);
        W.a[mf][1] = *(const bf16x8*)(base + aoffX[mf] + 32);
      }
    } else {
      const __hip_bfloat16* base = spkt + (k0 - IN_F);
#pragma unroll
      for (int mf = 0; mf < 4; ++mf) {
        W.a[mf][0] = *(const bf16x8*)(base + aoffS[mf]);
        W.a[mf][1] = *(const bf16x8*)(base + aoffS[mf] + 32);
      }
    }
    W.bh[0] = *(const bf16x8*)(pBh + k0);
    W.bh[1] = *(const bf16x8*)(pBh + k0 + 32);
    W.bl[0] = *(const bf16x8*)(pBl + k0);
    W.bl[1] = *(const bf16x8*)(pBl + k0 + 32);
  };

  auto COMPW = [&](Win& W) {
#pragma unroll
    for (int s = 0; s < 2; ++s) {
#pragma unroll
      for (int mf = 0; mf < 4; ++mf) {
        acc[mf] = __builtin_amdgcn_mfma_f32_16x16x32_bf16(W.a[mf][s], W.bh[s],
                                                          acc[mf], 0, 0, 0);
        acc[mf] = __builtin_amdgcn_mfma_f32_16x16x32_bf16(W.a[mf][s], W.bl[s],
                                                          acc[mf], 0, 0, 0);
      }
    }
  };

  LOADW(0, wn0);
  LOADW(1, wn1);
  LOADW(2, wn2);
#define ITER(i, W)                        \
  COMPW(W);                               \
  if ((i) + 3 < NIT_B) LOADW((i) + 3, W);
  ITER(0, wn0) ITER(1, wn1) ITER(2, wn2)
  ITER(3, wn0) ITER(4, wn1) ITER(5, wn2)
  ITER(6, wn0) ITER(7, wn1) ITER(8, wn2)
  ITER(9, wn0)
#undef ITER

  __syncthreads();
#pragma unroll
  for (int mf = 0; mf < 4; ++mf) {
#pragma unroll
    for (int q = 0; q < 4; ++q) {
      const int m = mf * 16 + (l >> 4) * 4 + q;
      red[wv * 1024 + m * 16 + fr] = acc[mf][q];
    }
  }
  __syncthreads();

  __hip_bfloat16* spk_out = spk + (size_t)(t + 1) * BATCH * HID;
#pragma unroll
  for (int u = 0; u < 2; ++u) {
    const int o = tid + u * 512;
    float c = red[o];
#pragma unroll
    for (int k2 = 1; k2 < NWAVE_B; ++k2) c += red[k2 * 1024 + o];
    const int m  = o >> 4;
    const int ng = nbase + (o & 15);
    const size_t gi = (size_t)m * HID + ng;
    float mv = mem1[gi] - beta[ng] + c;
    mv = fmaxf(mv, 0.f);
    const float s = (mv > thr[ng]) ? 1.f : 0.f;
    mv -= s * thr[ng];
    mem1[gi] = mv;
    spk_out[gi] = __float2bfloat16(s);
  }
}

// ---------------- readout GEMM v2 (unchanged from round 4) ----------------
__global__ __launch_bounds__(256, 2)
void k_ro_gemm(const __hip_bfloat16* __restrict__ A,
               const __hip_bfloat16* __restrict__ w2hi,
               const __hip_bfloat16* __restrict__ w2lo,
               const float* __restrict__ b2,
               float* __restrict__ cur2) {
  __shared__ __align__(16) short lA[2][64 * BK];
  __shared__ __align__(16) short lBh[2][64 * BK];
  __shared__ __align__(16) short lBl[2][64 * BK];

  const int tid  = threadIdx.x;
  const int lane = tid & 63;
  const int w    = tid >> 6;

  const int xcd = blockIdx.x & 7;
  const int c   = blockIdx.x >> 3;
  const int mt  = xcd * 16 + (c >> 3);
  const int nt  = c & 7;
  const int mbase = mt * 64;
  const int nbase = nt * 64;

  const int rS   = tid >> 2;
  const int cEl  = (tid & 3) * 16;
  const int swzX = (rS & 7) << 4;
  const int stByte0 = rS * 128 + ((cEl * 2) ^ swzX);
  const int stByte1 = rS * 128 + ((cEl * 2 + 16) ^ swzX);

  const int fr    = lane & 15;
  const int fkB   = (lane >> 4) * 16;
  const int frSwz = (fr & 7) << 4;

  f32x4 acc[4];
#pragma unroll
  for (int m = 0; m < 4; ++m) acc[m] = (f32x4){0.f, 0.f, 0.f, 0.f};
  bf16x8 rgA[6], rgB[6];

  auto GLOAD = [&](int it, bf16x8* R) {
    const int k0 = it * BK;
    const __hip_bfloat16* asrc = A    + (size_t)(mbase + rS) * HID + k0 + cEl;
    const __hip_bfloat16* hsrc = w2hi + (size_t)(nbase + rS) * HID + k0 + cEl;
    const __hip_bfloat16* lsrc = w2lo + (size_t)(nbase + rS) * HID + k0 + cEl;
    R[0] = *(const bf16x8*)(asrc);
    R[1] = *(const bf16x8*)(asrc + 8);
    R[2] = *(const bf16x8*)(hsrc);
    R[3] = *(const bf16x8*)(hsrc + 8);
    R[4] = *(const bf16x8*)(lsrc);
    R[5] = *(const bf16x8*)(lsrc + 8);
  };
  auto DSWRITE = [&](int ibuf, bf16x8* R) {
    *(bf16x8*)((char*)lA[ibuf] + stByte0)  = R[0];
    *(bf16x8*)((char*)lA[ibuf] + stByte1)  = R[1];
    *(bf16x8*)((char*)lBh[ibuf] + stByte0) = R[2];
    *(bf16x8*)((char*)lBh[ibuf] + stByte1) = R[3];
    *(bf16x8*)((char*)lBl[ibuf] + stByte0) = R[4];
    *(bf16x8*)((char*)lBl[ibuf] + stByte1) = R[5];
  };
  auto COMPUTE = [&](int ibuf) {
    const char* pA  = (const char*)lA[ibuf];
    const char* pBh = (const char*)lBh[ibuf];
    const char* pBl = (const char*)lBl[ibuf];
#pragma unroll
    for (int s = 0; s < 2; ++s) {
      const int co = ((s * 64 + fkB) ^ frSwz);
      bf16x8 fbh = *(const bf16x8*)(pBh + (w * 16 + fr) * 128 + co);
      bf16x8 fbl = *(const bf16x8*)(pBl + (w * 16 + fr) * 128 + co);
#pragma unroll
      for (int m = 0; m < 4; ++m) {
        bf16x8 fa = *(const bf16x8*)(pA + (m * 16 + fr) * 128 + co);
        acc[m] = __builtin_amdgcn_mfma_f32_16x16x32_bf16(fa, fbh, acc[m], 0, 0, 0);
        acc[m] = __builtin_amdgcn_mfma_f32_16x16x32_bf16(fa, fbl, acc[m], 0, 0, 0);
      }
    }
  };

  constexpr int RNIT = HID / BK;  // 64
  GLOAD(0, rgA);
  DSWRITE(0, rgA);
  __syncthreads();
  for (int itp = 0; itp < RNIT / 2; ++itp) {
    const int it = itp * 2;
    GLOAD(it + 1, rgB);
    COMPUTE(0);
    DSWRITE(1, rgB);
    __syncthreads();
    if (it + 2 < RNIT) {
      GLOAD(it + 2, rgA);
      COMPUTE(1);
      DSWRITE(0, rgA);
      __syncthreads();
    } else {
      COMPUTE(1);
    }
  }

  const int col = nbase + w * 16 + fr;
  const float bias = b2[col];
  const int brow = (lane >> 4) * 4;
#pragma unroll
  for (int m = 0; m < 4; ++m) {
#pragma unroll
    for (int q = 0; q < 4; ++q) {
      const int row = mbase + m * 16 + brow + q;
      cur2[(size_t)row * OUT_F + col] = acc[m][q] + bias;
    }
  }
}

// ---------------- readout LIF scan ----------------
__global__ void k_ro_scan(const float* __restrict__ cur2,
                          const float* __restrict__ beta,
                          const float* __restrict__ thr,
                          float* __restrict__ out) {
  const int i = blockIdx.x * blockDim.x + threadIdx.x;
  const int b = i >> 9;
  const int o = i & (OUT_F - 1);
  const float bt = beta[o];
  const float th = thr[o];
  float m = 0.0f;
  for (int t = 0; t < T_STEPS; ++t) {
    const size_t idx = (size_t)(t * BATCH + b) * OUT_F + o;
    m = m - bt + cur2[idx];
    const float s = (m > th) ? 1.0f : 0.0f;
    m -= s * th;
    out[idx] = s;
  }
}

// ---------------- launch ----------------
extern "C" void kernel_launch(void* const* d_in, const int* in_sizes, int n_in,
                              void* d_out, int out_size, void* d_ws, size_t ws_size,
                              hipStream_t stream) {
  const float* x        = (const float*)d_in[0];
  const float* w1       = (const float*)d_in[1];
  const float* w2       = (const float*)d_in[2];
  const float* b2       = (const float*)d_in[3];
  const float* beta_lsm = (const float*)d_in[4];
  const float* thr_lsm  = (const float*)d_in[5];
  const float* beta_ro  = (const float*)d_in[6];
  const float* thr_ro   = (const float*)d_in[7];
  float* out = (float*)d_out;

  char* ws = (char*)d_ws;
  size_t off = 0;
  auto alloc = [&](size_t bytes) -> char* {
    char* p = ws + off;
    off += (bytes + 255) & ~(size_t)255;
    return p;
  };
  __hip_bfloat16* w1hi = (__hip_bfloat16*)alloc((size_t)HID * TOTAL * 2);
  __hip_bfloat16* w1lo = (__hip_bfloat16*)alloc((size_t)HID * TOTAL * 2);
  __hip_bfloat16* xb   = (__hip_bfloat16*)alloc((size_t)T_STEPS * BATCH * IN_F * 2);
  __hip_bfloat16* spk  = (__hip_bfloat16*)alloc((size_t)(T_STEPS + 1) * BATCH * HID * 2);
  __hip_bfloat16* w2hi = (__hip_bfloat16*)alloc((size_t)OUT_F * HID * 2);
  __hip_bfloat16* w2lo = (__hip_bfloat16*)alloc((size_t)OUT_F * HID * 2);
  float* mem1 = (float*)alloc((size_t)BATCH * HID * 4);
  float* cur2 = (float*)alloc((size_t)T_STEPS * BATCH * OUT_F * 4);

  // prep
  {
    int n4 = HID * TOTAL / 4;
    k_cvt_split<<<(n4 + 255) / 256, 256, 0, stream>>>(w1, w1hi, w1lo, n4);
  }
  {
    int n4 = OUT_F * HID / 4;
    k_cvt_split<<<(n4 + 255) / 256, 256, 0, stream>>>(w2, w2hi, w2lo, n4);
  }
  {
    int n = T_STEPS * BATCH * IN_F;
    k_cvt_x<<<(n + 255) / 256, 256, 0, stream>>>(x, xb, n);
  }
  {
    int n = BATCH * HID;
    k_zero<<<(n + 255) / 256, 256, 0, stream>>>(mem1, (ushort*)spk, n);
  }

  // sequential reservoir steps: A/B split (even t = LDS kernel, odd = gather)
  for (int t = 0; t < T_STEPS; ++t) {
    if (t & 1) {
      k_stepB<<<HID / 16, 512, 0, stream>>>(t, xb, spk, w1hi, w1lo, mem1,
                                            beta_lsm, thr_lsm);
    } else {
      k_stepA<<<HID / 16, 256, 0, stream>>>(t, xb, spk, w1hi, w1lo, mem1,
                                            beta_lsm, thr_lsm);
    }
  }

  // readout
  k_ro_gemm<<<(T_STEPS * BATCH / 64) * (OUT_F / 64), 256, 0, stream>>>(
      spk + (size_t)BATCH * HID, w2hi, w2lo, b2, cur2);
  k_ro_scan<<<(BATCH * OUT_F) / 256, 256, 0, stream>>>(cur2, beta_ro, thr_ro, out);
}

// Round 7
// 2437.297 us; speedup vs baseline: 1.6150x; 1.2850x over previous
//
#include <hip/hip_runtime.h>
#include <hip/hip_bf16.h>

// LSMPool round 7 (= round-6 retry; fix: bf16 spike write via raw bit pattern
// 0x3F80/0x0000 instead of the non-existent __hip_bfloat16::data member).
//   k_fc1: 256 blocks = 64 n-chunks (N=64) x 4 k-splits (K=1280).
//     A-broadcast traffic 167->41 MB/step; w1 read once.
//     4 waves share each staged window (A 8K + Bh 8K + Bl 8K, BK=64),
//     depth-3 bufs (72KB LDS), gload_lds w/ pre-swizzled src, counted
//     vmcnt(6) + RAW s_barrier (no vmcnt(0) drain).
//   k_fc1_red: partial reduce (fixed ks order) + LIF + spike write, fused.
//   ro_gemm v2 (104us, 0 bank conflicts) / prep / ro_scan unchanged.

namespace {
constexpr int T_STEPS = 128;
constexpr int BATCH   = 64;
constexpr int IN_F    = 1024;
constexpr int HID     = 4096;
constexpr int OUT_F   = 512;
constexpr int TOTAL   = IN_F + HID;    // 5120
constexpr int BK      = 64;
constexpr int KSPL    = 4;
constexpr int KRANGE  = TOTAL / KSPL;  // 1280
constexpr int NWIN    = KRANGE / BK;   // 20
constexpr int BUFB    = 24576;         // A 8K | Bh 8K | Bl 8K
constexpr int NBUF    = 3;             // 73728 B LDS
}

using bf16x8 = __attribute__((ext_vector_type(8))) short;
using f32x4  = __attribute__((ext_vector_type(4))) float;

__device__ __forceinline__ void gload_lds16(const void* g, void* l) {
  __builtin_amdgcn_global_load_lds(
      (const __attribute__((address_space(1))) unsigned int*)(g),
      (__attribute__((address_space(3))) unsigned int*)(l), 16, 0, 0);
}

// ---------------- prep kernels ----------------

__global__ void k_cvt_split(const float* __restrict__ src,
                            __hip_bfloat16* __restrict__ hi,
                            __hip_bfloat16* __restrict__ lo, int n4) {
  int i = blockIdx.x * blockDim.x + threadIdx.x;
  if (i >= n4) return;
  float4 v = reinterpret_cast<const float4*>(src)[i];
#define CVT1(J, F)                                                        \
  {                                                                       \
    __hip_bfloat16 hb = __float2bfloat16(F);                              \
    hi[4 * (size_t)i + J] = hb;                                           \
    lo[4 * (size_t)i + J] = __float2bfloat16((F) - __bfloat162float(hb)); \
  }
  CVT1(0, v.x) CVT1(1, v.y) CVT1(2, v.z) CVT1(3, v.w)
#undef CVT1
}

__global__ void k_cvt_x(const float* __restrict__ src,
                        __hip_bfloat16* __restrict__ dst, int n) {
  int i = blockIdx.x * blockDim.x + threadIdx.x;
  if (i >= n) return;
  dst[i] = __float2bfloat16(src[i]);
}

__global__ void k_zero(float* __restrict__ mem1, ushort* __restrict__ spk0, int n) {
  int i = blockIdx.x * blockDim.x + threadIdx.x;
  if (i >= n) return;
  mem1[i] = 0.0f;
  spk0[i] = 0;  // bf16 +0.0
}

// ---------------- fc1 K-split GEMM ----------------
// block = (nchunk = blockIdx&63 -> N=64, ks = blockIdx>>6 -> K=1280).
// 4 waves: wave wv computes n-sub [wv*16, wv*16+16) for all 64 batch rows.
// Staged window (shared): A[64][64] + Bh[64][64] + Bl[64][64] bf16, each
// row 128 B, 16B-chunk c of row r stored at chunk (c ^ (r&7)) [src-preswizzle].
__global__ __launch_bounds__(256, 1)
void k_fc1(int t,
           const __hip_bfloat16* __restrict__ xb,    // [T][B][IN_F]
           const __hip_bfloat16* __restrict__ spk,   // [T+1][B][HID]
           const __hip_bfloat16* __restrict__ w1hi,  // [HID][TOTAL]
           const __hip_bfloat16* __restrict__ w1lo,
           float* __restrict__ part) {               // [KSPL][B][HID]
  __shared__ __align__(16) char smem[NBUF * BUFB];

  const int tid = threadIdx.x;
  const int l   = tid & 63;
  const int wv  = tid >> 6;
  const int nchunk = blockIdx.x & 63;
  const int ks     = blockIdx.x >> 6;
  const int nbase  = nchunk * 64;
  const int kbase  = ks * KRANGE;

  const __hip_bfloat16* xbt  = xb  + (size_t)t * BATCH * IN_F;
  const __hip_bfloat16* spkt = spk + (size_t)t * BATCH * HID;

  // staging: one gload_lds16 per wave = one 8-row x 64-col slab (1KB).
  // wave wv stages slabs {2wv, 2wv+1} of each of A / Bh / Bl (6 loads/wave).
  const int row8 = l >> 3;                  // row within slab
  const int cswz = ((l & 7) ^ row8) * 8;    // pre-swizzled chunk (elem offset)
  const int s0 = 2 * wv, s1 = 2 * wv + 1;
  const int rA0 = s0 * 8 + row8;            // tile rows staged by this lane
  const int rA1 = s1 * 8 + row8;

  // fragment geometry
  const int fr  = l & 15;
  const int fks = l >> 4;                   // chunk-in-ksub 0..3
  const int f7  = fr & 7;

  f32x4 acc[4];
#pragma unroll
  for (int mf = 0; mf < 4; ++mf) acc[mf] = (f32x4){0.f, 0.f, 0.f, 0.f};

  auto ISSUE = [&](int iw, char* buf) {
    const int k0 = kbase + iw * BK;         // windows never straddle x/spk
    if (k0 < IN_F) {
      gload_lds16(xbt + (size_t)rA0 * IN_F + k0 + cswz, buf + s0 * 1024);
      gload_lds16(xbt + (size_t)rA1 * IN_F + k0 + cswz, buf + s1 * 1024);
    } else {
      const int kh = k0 - IN_F;
      gload_lds16(spkt + (size_t)rA0 * HID + kh + cswz, buf + s0 * 1024);
      gload_lds16(spkt + (size_t)rA1 * HID + kh + cswz, buf + s1 * 1024);
    }
    gload_lds16(w1hi + (size_t)(nbase + rA0) * TOTAL + k0 + cswz,
                buf + 8192 + s0 * 1024);
    gload_lds16(w1hi + (size_t)(nbase + rA1) * TOTAL + k0 + cswz,
                buf + 8192 + s1 * 1024);
    gload_lds16(w1lo + (size_t)(nbase + rA0) * TOTAL + k0 + cswz,
                buf + 16384 + s0 * 1024);
    gload_lds16(w1lo + (size_t)(nbase + rA1) * TOTAL + k0 + cswz,
                buf + 16384 + s1 * 1024);
  };

  auto COMP = [&](const char* buf) {
    const int browB = wv * 16 + fr;
#pragma unroll
    for (int s = 0; s < 2; ++s) {
      const int co = ((s * 4 + fks) ^ f7) * 16;
      bf16x8 bh = *(const bf16x8*)(buf + 8192  + browB * 128 + co);
      bf16x8 bl = *(const bf16x8*)(buf + 16384 + browB * 128 + co);
#pragma unroll
      for (int mf = 0; mf < 4; ++mf) {
        bf16x8 a = *(const bf16x8*)(buf + (mf * 16 + fr) * 128 + co);
        acc[mf] = __builtin_amdgcn_mfma_f32_16x16x32_bf16(a, bh, acc[mf], 0, 0, 0);
        acc[mf] = __builtin_amdgcn_mfma_f32_16x16x32_bf16(a, bl, acc[mf], 0, 0, 0);
      }
    }
  };

  // depth-3 pipeline: counted vmcnt (never 0 mid-loop) + raw s_barrier.
  ISSUE(0, smem);
  ISSUE(1, smem + BUFB);
  for (int i = 0; i < NWIN; ++i) {
    if (i + 1 < NWIN) {
      asm volatile("s_waitcnt vmcnt(6)" ::: "memory");   // window i landed
    } else {
      asm volatile("s_waitcnt vmcnt(0)" ::: "memory");   // last window
    }
    __builtin_amdgcn_s_barrier();          // all waves' window-i loads visible
    asm volatile("" ::: "memory");
    const char* bufc = smem + (i % 3) * BUFB;
    COMP(bufc);
    if (i + 2 < NWIN) ISSUE(i + 2, smem + ((i + 2) % 3) * BUFB);
  }

  // write K-split partial. C/D layout: col(lane&15)=n, row=(lane>>4)*4+q=batch.
  float* pp = part + (size_t)ks * (BATCH * HID) + nbase + wv * 16 + fr;
  const int brow = (l >> 4) * 4;
#pragma unroll
  for (int mf = 0; mf < 4; ++mf) {
#pragma unroll
    for (int q = 0; q < 4; ++q) {
      pp[(size_t)(mf * 16 + brow + q) * HID] = acc[mf][q];
    }
  }
}

// ---------------- fc1 partial-reduce + LIF (fused) ----------------
// 256 blocks x 256 thr x 4 elems = 262144 = B*HID. Fixed ks order.
// Spikes are exactly 0.0/1.0 -> write bf16 bit patterns 0x0000/0x3F80.
__global__ __launch_bounds__(256)
void k_fc1_red(const float* __restrict__ part,   // [KSPL][B][HID]
               float* __restrict__ mem1,         // [B][HID]
               const float* __restrict__ beta,   // [HID]
               const float* __restrict__ thr,    // [HID]
               ushort* __restrict__ spk_out) {   // [B][HID] bf16 bits
  const int i0 = (blockIdx.x * 256 + threadIdx.x) * 4;
  constexpr int PS = BATCH * HID;  // 262144
  float4 c  = *(const float4*)(part + i0);
  float4 c1 = *(const float4*)(part + PS + i0);
  float4 c2 = *(const float4*)(part + 2 * PS + i0);
  float4 c3 = *(const float4*)(part + 3 * PS + i0);
  c.x += c1.x; c.y += c1.y; c.z += c1.z; c.w += c1.w;
  c.x += c2.x; c.y += c2.y; c.z += c2.z; c.w += c2.w;
  c.x += c3.x; c.y += c3.y; c.z += c3.z; c.w += c3.w;

  const int n0 = i0 & (HID - 1);
  const float4 bt = *(const float4*)(beta + n0);
  const float4 th = *(const float4*)(thr + n0);
  float4 mv = *(float4*)(mem1 + i0);

  ushort4 so;
#define LIF1(COMP_M, COMP_B, COMP_T, SOUT)                  \
  {                                                         \
    float m2 = COMP_M - COMP_B + c.SOUT;                    \
    m2 = fmaxf(m2, 0.f);                                    \
    const bool sp = (m2 > COMP_T);                          \
    if (sp) m2 -= COMP_T;                                   \
    COMP_M = m2;                                            \
    so.SOUT = sp ? (ushort)0x3F80 : (ushort)0;              \
  }
  LIF1(mv.x, bt.x, th.x, x)
  LIF1(mv.y, bt.y, th.y, y)
  LIF1(mv.z, bt.z, th.z, z)
  LIF1(mv.w, bt.w, th.w, w)
#undef LIF1
  *(float4*)(mem1 + i0) = mv;
  *(ushort4*)(spk_out + i0) = so;
}

// ---------------- readout GEMM v2 (unchanged) ----------------
__global__ __launch_bounds__(256, 2)
void k_ro_gemm(const __hip_bfloat16* __restrict__ A,
               const __hip_bfloat16* __restrict__ w2hi,
               const __hip_bfloat16* __restrict__ w2lo,
               const float* __restrict__ b2,
               float* __restrict__ cur2) {
  __shared__ __align__(16) short lA[2][64 * BK];
  __shared__ __align__(16) short lBh[2][64 * BK];
  __shared__ __align__(16) short lBl[2][64 * BK];

  const int tid  = threadIdx.x;
  const int lane = tid & 63;
  const int w    = tid >> 6;

  const int xcd = blockIdx.x & 7;
  const int c   = blockIdx.x >> 3;
  const int mt  = xcd * 16 + (c >> 3);
  const int nt  = c & 7;
  const int mbase = mt * 64;
  const int nbase = nt * 64;

  const int rS   = tid >> 2;
  const int cEl  = (tid & 3) * 16;
  const int swzX = (rS & 7) << 4;
  const int stByte0 = rS * 128 + ((cEl * 2) ^ swzX);
  const int stByte1 = rS * 128 + ((cEl * 2 + 16) ^ swzX);

  const int fr    = lane & 15;
  const int fkB   = (lane >> 4) * 16;
  const int frSwz = (fr & 7) << 4;

  f32x4 acc[4];
#pragma unroll
  for (int m = 0; m < 4; ++m) acc[m] = (f32x4){0.f, 0.f, 0.f, 0.f};
  bf16x8 rgA[6], rgB[6];

  auto GLOAD = [&](int it, bf16x8* R) {
    const int k0 = it * BK;
    const __hip_bfloat16* asrc = A    + (size_t)(mbase + rS) * HID + k0 + cEl;
    const __hip_bfloat16* hsrc = w2hi + (size_t)(nbase + rS) * HID + k0 + cEl;
    const __hip_bfloat16* lsrc = w2lo + (size_t)(nbase + rS) * HID + k0 + cEl;
    R[0] = *(const bf16x8*)(asrc);
    R[1] = *(const bf16x8*)(asrc + 8);
    R[2] = *(const bf16x8*)(hsrc);
    R[3] = *(const bf16x8*)(hsrc + 8);
    R[4] = *(const bf16x8*)(lsrc);
    R[5] = *(const bf16x8*)(lsrc + 8);
  };
  auto DSWRITE = [&](int ibuf, bf16x8* R) {
    *(bf16x8*)((char*)lA[ibuf] + stByte0)  = R[0];
    *(bf16x8*)((char*)lA[ibuf] + stByte1)  = R[1];
    *(bf16x8*)((char*)lBh[ibuf] + stByte0) = R[2];
    *(bf16x8*)((char*)lBh[ibuf] + stByte1) = R[3];
    *(bf16x8*)((char*)lBl[ibuf] + stByte0) = R[4];
    *(bf16x8*)((char*)lBl[ibuf] + stByte1) = R[5];
  };
  auto COMPUTE = [&](int ibuf) {
    const char* pA  = (const char*)lA[ibuf];
    const char* pBh = (const char*)lBh[ibuf];
    const char* pBl = (const char*)lBl[ibuf];
#pragma unroll
    for (int s = 0; s < 2; ++s) {
      const int co = ((s * 64 + fkB) ^ frSwz);
      bf16x8 fbh = *(const bf16x8*)(pBh + (w * 16 + fr) * 128 + co);
      bf16x8 fbl = *(const bf16x8*)(pBl + (w * 16 + fr) * 128 + co);
#pragma unroll
      for (int m = 0; m < 4; ++m) {
        bf16x8 fa = *(const bf16x8*)(pA + (m * 16 + fr) * 128 + co);
        acc[m] = __builtin_amdgcn_mfma_f32_16x16x32_bf16(fa, fbh, acc[m], 0, 0, 0);
        acc[m] = __builtin_amdgcn_mfma_f32_16x16x32_bf16(fa, fbl, acc[m], 0, 0, 0);
      }
    }
  };

  constexpr int RNIT = HID / BK;  // 64
  GLOAD(0, rgA);
  DSWRITE(0, rgA);
  __syncthreads();
  for (int itp = 0; itp < RNIT / 2; ++itp) {
    const int it = itp * 2;
    GLOAD(it + 1, rgB);
    COMPUTE(0);
    DSWRITE(1, rgB);
    __syncthreads();
    if (it + 2 < RNIT) {
      GLOAD(it + 2, rgA);
      COMPUTE(1);
      DSWRITE(0, rgA);
      __syncthreads();
    } else {
      COMPUTE(1);
    }
  }

  const int col = nbase + w * 16 + fr;
  const float bias = b2[col];
  const int brow = (lane >> 4) * 4;
#pragma unroll
  for (int m = 0; m < 4; ++m) {
#pragma unroll
    for (int q = 0; q < 4; ++q) {
      const int row = mbase + m * 16 + brow + q;
      cur2[(size_t)row * OUT_F + col] = acc[m][q] + bias;
    }
  }
}

// ---------------- readout LIF scan ----------------
__global__ void k_ro_scan(const float* __restrict__ cur2,
                          const float* __restrict__ beta,
                          const float* __restrict__ thr,
                          float* __restrict__ out) {
  const int i = blockIdx.x * blockDim.x + threadIdx.x;
  const int b = i >> 9;
  const int o = i & (OUT_F - 1);
  const float bt = beta[o];
  const float th = thr[o];
  float m = 0.0f;
  for (int t = 0; t < T_STEPS; ++t) {
    const size_t idx = (size_t)(t * BATCH + b) * OUT_F + o;
    m = m - bt + cur2[idx];
    const float s = (m > th) ? 1.0f : 0.0f;
    m -= s * th;
    out[idx] = s;
  }
}

// ---------------- launch ----------------
extern "C" void kernel_launch(void* const* d_in, const int* in_sizes, int n_in,
                              void* d_out, int out_size, void* d_ws, size_t ws_size,
                              hipStream_t stream) {
  const float* x        = (const float*)d_in[0];
  const float* w1       = (const float*)d_in[1];
  const float* w2       = (const float*)d_in[2];
  const float* b2       = (const float*)d_in[3];
  const float* beta_lsm = (const float*)d_in[4];
  const float* thr_lsm  = (const float*)d_in[5];
  const float* beta_ro  = (const float*)d_in[6];
  const float* thr_ro   = (const float*)d_in[7];
  float* out = (float*)d_out;

  char* ws = (char*)d_ws;
  size_t off = 0;
  auto alloc = [&](size_t bytes) -> char* {
    char* p = ws + off;
    off += (bytes + 255) & ~(size_t)255;
    return p;
  };
  __hip_bfloat16* w1hi = (__hip_bfloat16*)alloc((size_t)HID * TOTAL * 2);
  __hip_bfloat16* w1lo = (__hip_bfloat16*)alloc((size_t)HID * TOTAL * 2);
  __hip_bfloat16* xb   = (__hip_bfloat16*)alloc((size_t)T_STEPS * BATCH * IN_F * 2);
  __hip_bfloat16* spk  = (__hip_bfloat16*)alloc((size_t)(T_STEPS + 1) * BATCH * HID * 2);
  __hip_bfloat16* w2hi = (__hip_bfloat16*)alloc((size_t)OUT_F * HID * 2);
  __hip_bfloat16* w2lo = (__hip_bfloat16*)alloc((size_t)OUT_F * HID * 2);
  float* mem1 = (float*)alloc((size_t)BATCH * HID * 4);
  float* cur2 = (float*)alloc((size_t)T_STEPS * BATCH * OUT_F * 4);
  float* part = (float*)alloc((size_t)KSPL * BATCH * HID * 4);

  // prep
  {
    int n4 = HID * TOTAL / 4;
    k_cvt_split<<<(n4 + 255) / 256, 256, 0, stream>>>(w1, w1hi, w1lo, n4);
  }
  {
    int n4 = OUT_F * HID / 4;
    k_cvt_split<<<(n4 + 255) / 256, 256, 0, stream>>>(w2, w2hi, w2lo, n4);
  }
  {
    int n = T_STEPS * BATCH * IN_F;
    k_cvt_x<<<(n + 255) / 256, 256, 0, stream>>>(x, xb, n);
  }
  {
    int n = BATCH * HID;
    k_zero<<<(n + 255) / 256, 256, 0, stream>>>(mem1, (ushort*)spk, n);
  }

  // sequential reservoir steps: K-split GEMM + fused reduce/LIF per step
  for (int t = 0; t < T_STEPS; ++t) {
    k_fc1<<<64 * KSPL, 256, 0, stream>>>(t, xb, spk, w1hi, w1lo, part);
    k_fc1_red<<<BATCH * HID / (256 * 4), 256, 0, stream>>>(
        part, mem1, beta_lsm, thr_lsm,
        (ushort*)(spk + (size_t)(t + 1) * BATCH * HID));
  }

  // readout
  k_ro_gemm<<<(T_STEPS * BATCH / 64) * (OUT_F / 64), 256, 0, stream>>>(
      spk + (size_t)BATCH * HID, w2hi, w2lo, b2, cur2);
  k_ro_scan<<<(BATCH * OUT_F) / 256, 256, 0, stream>>>(cur2, beta_ro, thr_ro, out);
}